// Round 1
// baseline (704.022 us; speedup 1.0000x reference)
//
#include <hip/hip_runtime.h>
#include <cstdio>

#define NN 100000
#define NE 1600000
#define IN_DIM 256
#define HID_DIM 128
#define OUT_DIM 64

// ---------------- degree count ----------------
__global__ __launch_bounds__(256) void deg_kernel(const int* __restrict__ src,
                                                  const int* __restrict__ dst,
                                                  unsigned* __restrict__ cnt_out,
                                                  unsigned* __restrict__ cnt_in) {
    int e = blockIdx.x * 256 + threadIdx.x;
    if (e < NE) {
        atomicAdd(&cnt_out[src[e]], 1u);
        atomicAdd(&cnt_in[dst[e]], 1u);
    }
}

// ---------------- scan (3 stages), tile = 1024 ----------------
__global__ __launch_bounds__(256) void scan1_kernel(const unsigned* __restrict__ cnt,
                                                    unsigned* __restrict__ pre,
                                                    unsigned* __restrict__ tsums, int n) {
    __shared__ unsigned sdata[256];
    int t = threadIdx.x;
    int base = blockIdx.x * 1024 + t * 4;
    unsigned v[4];
    unsigned s = 0;
#pragma unroll
    for (int i = 0; i < 4; ++i) {
        unsigned x = (base + i < n) ? cnt[base + i] : 0u;
        v[i] = s;
        s += x;
    }
    sdata[t] = s;
    __syncthreads();
    for (int o = 1; o < 256; o <<= 1) {
        unsigned add = (t >= o) ? sdata[t - o] : 0u;
        __syncthreads();
        sdata[t] += add;
        __syncthreads();
    }
    unsigned incl = sdata[t];
    unsigned excl = incl - s;
#pragma unroll
    for (int i = 0; i < 4; ++i) {
        int idx = base + i;
        if (idx < n) pre[idx] = excl + v[i];
    }
    if (t == 255) tsums[blockIdx.x] = incl;
}

__global__ __launch_bounds__(256) void scan2_kernel(unsigned* __restrict__ tsums, int nt) {
    __shared__ unsigned sdata[256];
    int t = threadIdx.x;
    unsigned s = (t < nt) ? tsums[t] : 0u;
    sdata[t] = s;
    __syncthreads();
    for (int o = 1; o < 256; o <<= 1) {
        unsigned add = (t >= o) ? sdata[t - o] : 0u;
        __syncthreads();
        sdata[t] += add;
        __syncthreads();
    }
    if (t < nt) tsums[t] = sdata[t] - s;  // exclusive
}

__global__ __launch_bounds__(256) void scan3_kernel(unsigned* __restrict__ row_start,
                                                    const unsigned* __restrict__ tsums,
                                                    unsigned* __restrict__ cursor,
                                                    const unsigned* __restrict__ cnt_in,
                                                    const unsigned* __restrict__ cnt_out,
                                                    float* __restrict__ dsin,
                                                    float* __restrict__ dsout, int n) {
    int i = blockIdx.x * 256 + threadIdx.x;
    if (i < n) {
        unsigned v = row_start[i] + tsums[i >> 10];
        row_start[i] = v;
        cursor[i] = v;
        unsigned ci = cnt_in[i]; if (ci < 1u) ci = 1u;
        unsigned co = cnt_out[i]; if (co < 1u) co = 1u;
        dsin[i] = rsqrtf((float)ci);
        dsout[i] = rsqrtf((float)co);
    }
    if (i == 0) row_start[n] = (unsigned)NE;
}

__global__ __launch_bounds__(256) void fill_kernel(const int* __restrict__ src,
                                                   const int* __restrict__ dst,
                                                   unsigned* __restrict__ cursor,
                                                   int* __restrict__ csr) {
    int e = blockIdx.x * 256 + threadIdx.x;
    if (e < NE) {
        int d = dst[e];
        unsigned pos = atomicAdd(&cursor[d], 1u);
        csr[pos] = src[e];
    }
}

// ---------------- GEMM: C[M,N] = (A .* scale) @ W, A[M,K], W[K,N] ----------------
template <int K, int N, bool SCALE>
__global__ __launch_bounds__(256) void gemm_kernel(const float* __restrict__ A,
                                                   const float* __restrict__ W,
                                                   const float* __restrict__ scale,
                                                   float* __restrict__ C, int M) {
    constexpr int BM = 64;
    constexpr int BK = 16;
    constexpr int CG = N / 4;        // col groups of float4
    constexpr int RPI = 256 / CG;    // rows covered per "iter"
    constexpr int RT = BM / RPI;     // row tiles per thread

    __shared__ float sA[BM][BK + 4];
    __shared__ float sW[BK][N];

    const int tid = threadIdx.x;
    const int m0 = blockIdx.x * BM;
    const int colg = tid % CG;
    const int row0 = tid / CG;

    float4 acc[RT];
#pragma unroll
    for (int i = 0; i < RT; ++i) acc[i] = make_float4(0.f, 0.f, 0.f, 0.f);

    const int la_m = tid / (BK / 4);
    const int la_k = (tid % (BK / 4)) * 4;

    for (int k0 = 0; k0 < K; k0 += BK) {
        // stage A tile (scaled)
        {
            int m = m0 + la_m;
            float4 av = make_float4(0.f, 0.f, 0.f, 0.f);
            if (m < M) {
                av = *reinterpret_cast<const float4*>(&A[(size_t)m * K + k0 + la_k]);
                if constexpr (SCALE) {
                    float s = scale[m];
                    av.x *= s; av.y *= s; av.z *= s; av.w *= s;
                }
            }
            *reinterpret_cast<float4*>(&sA[la_m][la_k]) = av;
        }
        // stage W tile
#pragma unroll
        for (int r = 0; r < (BK * N) / 1024; ++r) {
            int f = (tid + r * 256) * 4;
            int k = f / N, n = f % N;
            *reinterpret_cast<float4*>(&sW[k][n]) =
                *reinterpret_cast<const float4*>(&W[(size_t)(k0 + k) * N + n]);
        }
        __syncthreads();
#pragma unroll
        for (int kk = 0; kk < BK; ++kk) {
            float4 wv = *reinterpret_cast<const float4*>(&sW[kk][colg * 4]);
#pragma unroll
            for (int i = 0; i < RT; ++i) {
                float a = sA[row0 + i * RPI][kk];
                acc[i].x += a * wv.x;
                acc[i].y += a * wv.y;
                acc[i].z += a * wv.z;
                acc[i].w += a * wv.w;
            }
        }
        __syncthreads();
    }
#pragma unroll
    for (int i = 0; i < RT; ++i) {
        int m = m0 + row0 + i * RPI;
        if (m < M) *reinterpret_cast<float4*>(&C[(size_t)m * N + colg * 4]) = acc[i];
    }
}

// ---------------- SpMM layer 1: gather + fused relu(agg*dsin+b1)*dsout ----------------
__global__ __launch_bounds__(256) void spmm1_kernel(const float* __restrict__ feat,
                                                    const int* __restrict__ csr,
                                                    const unsigned* __restrict__ rs,
                                                    const float* __restrict__ dsin,
                                                    const float* __restrict__ dsout,
                                                    const float* __restrict__ b1,
                                                    float* __restrict__ xs) {
    int wave = threadIdx.x >> 6;
    int lane = threadIdx.x & 63;
    int node = blockIdx.x * 4 + wave;
    if (node >= NN) return;
    unsigned s0 = rs[node], s1 = rs[node + 1];
    int c = lane * 2;
    float ax = 0.f, ay = 0.f;
    for (unsigned j = s0; j < s1; ++j) {
        int s = csr[j];
        float2 v = *reinterpret_cast<const float2*>(&feat[(size_t)s * HID_DIM + c]);
        ax += v.x;
        ay += v.y;
    }
    float si = dsin[node], so = dsout[node];
    float x0 = fmaxf(ax * si + b1[c], 0.f) * so;
    float x1 = fmaxf(ay * si + b1[c + 1], 0.f) * so;
    *reinterpret_cast<float2*>(&xs[(size_t)node * HID_DIM + c]) = make_float2(x0, x1);
}

// ---------------- SpMM layer 2 + bias + softmax + writes ----------------
__global__ __launch_bounds__(256) void spmm2_kernel(const float* __restrict__ feat2,
                                                    const int* __restrict__ csr,
                                                    const unsigned* __restrict__ rs,
                                                    const float* __restrict__ dsin,
                                                    const float* __restrict__ b2,
                                                    float* __restrict__ out) {
    int wave = threadIdx.x >> 6;
    int lane = threadIdx.x & 63;
    int node = blockIdx.x * 4 + wave;
    if (node >= NN) return;
    unsigned s0 = rs[node], s1 = rs[node + 1];
    float acc = 0.f;
    for (unsigned j = s0; j < s1; ++j) {
        int s = csr[j];
        acc += feat2[(size_t)s * OUT_DIM + lane];
    }
    float logit = acc * dsin[node] + b2[lane];
    // softmax across 64 lanes
    float m = logit;
    for (int o = 32; o > 0; o >>= 1) m = fmaxf(m, __shfl_xor(m, o, 64));
    float e = __expf(logit - m);
    float sum = e;
    for (int o = 32; o > 0; o >>= 1) sum += __shfl_xor(sum, o, 64);
    float p = e / sum;
    out[(size_t)node * OUT_DIM + lane] = p;
    out[(size_t)NN * OUT_DIM + (size_t)node * OUT_DIM + lane] = logit;
}

static inline size_t align_up(size_t x, size_t a) { return (x + a - 1) & ~(a - 1); }

extern "C" void kernel_launch(void* const* d_in, const int* in_sizes, int n_in,
                              void* d_out, int out_size, void* d_ws, size_t ws_size,
                              hipStream_t stream) {
    (void)in_sizes; (void)n_in; (void)out_size;
    const float* h = (const float*)d_in[0];
    const float* W1 = (const float*)d_in[1];
    const float* b1 = (const float*)d_in[2];
    const float* W2 = (const float*)d_in[3];
    const float* b2 = (const float*)d_in[4];
    const int* src = (const int*)d_in[5];
    const int* dst = (const int*)d_in[6];
    float* out = (float*)d_out;

    char* ws = (char*)d_ws;
    size_t off = 0;
    auto alloc = [&](size_t bytes) {
        void* p = (void*)(ws + off);
        off = align_up(off + bytes, 512);
        return p;
    };
    unsigned* cnt_out = (unsigned*)alloc(NN * 4);
    unsigned* cnt_in = (unsigned*)alloc(NN * 4);
    unsigned* row_start = (unsigned*)alloc((NN + 1) * 4);
    unsigned* cursor = (unsigned*)alloc(NN * 4);
    unsigned* tsums = (unsigned*)alloc(256 * 4);
    float* dsout = (float*)alloc(NN * 4);
    float* dsin = (float*)alloc(NN * 4);
    int* csr = (int*)alloc((size_t)NE * 4);
    float* feat1 = (float*)alloc((size_t)NN * HID_DIM * 4);
    float* xs = (float*)alloc((size_t)NN * HID_DIM * 4);
    float* feat2 = feat1;  // alias: feat1 dead after spmm1

    if (off > ws_size) {
        fprintf(stderr, "kernel_launch: ws too small: need %zu, have %zu\n", off, ws_size);
        return;
    }

    hipMemsetAsync(cnt_out, 0, NN * 4, stream);
    hipMemsetAsync(cnt_in, 0, NN * 4, stream);

    deg_kernel<<<NE / 256, 256, 0, stream>>>(src, dst, cnt_out, cnt_in);

    const int tiles = (NN + 1023) / 1024;  // 98
    scan1_kernel<<<tiles, 256, 0, stream>>>(cnt_in, row_start, tsums, NN);
    scan2_kernel<<<1, 256, 0, stream>>>(tsums, tiles);
    scan3_kernel<<<(NN + 255) / 256, 256, 0, stream>>>(row_start, tsums, cursor, cnt_in,
                                                       cnt_out, dsin, dsout, NN);
    fill_kernel<<<NE / 256, 256, 0, stream>>>(src, dst, cursor, csr);

    gemm_kernel<IN_DIM, HID_DIM, true>
        <<<(NN + 63) / 64, 256, 0, stream>>>(h, W1, dsout, feat1, NN);
    spmm1_kernel<<<(NN + 3) / 4, 256, 0, stream>>>(feat1, csr, row_start, dsin, dsout, b1, xs);
    gemm_kernel<HID_DIM, OUT_DIM, false>
        <<<(NN + 63) / 64, 256, 0, stream>>>(xs, W2, nullptr, feat2, NN);
    spmm2_kernel<<<(NN + 3) / 4, 256, 0, stream>>>(feat2, csr, row_start, dsin, b2, out);
}

// Round 2
// 515.096 us; speedup vs baseline: 1.3668x; 1.3668x over previous
//
#include <hip/hip_runtime.h>
#include <cstdio>

#define NN 100000
#define NE 1600000
#define IN_DIM 256
#define HID_DIM 128
#define OUT_DIM 64

typedef short s8v __attribute__((ext_vector_type(8)));
typedef float f4v __attribute__((ext_vector_type(4)));
typedef unsigned short u16x4 __attribute__((ext_vector_type(4)));
typedef unsigned short u16x8 __attribute__((ext_vector_type(8)));

__device__ __forceinline__ unsigned short f2bf(float f) {
    unsigned u = __builtin_bit_cast(unsigned, f);
    u += 0x7FFFu + ((u >> 16) & 1u);  // RNE
    return (unsigned short)(u >> 16);
}
__device__ __forceinline__ float bf2f(unsigned short s) {
    unsigned u = ((unsigned)s) << 16;
    return __builtin_bit_cast(float, u);
}

// ---------------- degree count ----------------
__global__ __launch_bounds__(256) void deg_kernel(const int* __restrict__ src,
                                                  const int* __restrict__ dst,
                                                  unsigned* __restrict__ cnt_out,
                                                  unsigned* __restrict__ cnt_in) {
    int e = blockIdx.x * 256 + threadIdx.x;
    if (e < NE) {
        atomicAdd(&cnt_out[src[e]], 1u);
        atomicAdd(&cnt_in[dst[e]], 1u);
    }
}

// ---------------- scan (3 stages), tile = 1024 ----------------
__global__ __launch_bounds__(256) void scan1_kernel(const unsigned* __restrict__ cnt,
                                                    unsigned* __restrict__ pre,
                                                    unsigned* __restrict__ tsums, int n) {
    __shared__ unsigned sdata[256];
    int t = threadIdx.x;
    int base = blockIdx.x * 1024 + t * 4;
    unsigned v[4];
    unsigned s = 0;
#pragma unroll
    for (int i = 0; i < 4; ++i) {
        unsigned x = (base + i < n) ? cnt[base + i] : 0u;
        v[i] = s;
        s += x;
    }
    sdata[t] = s;
    __syncthreads();
    for (int o = 1; o < 256; o <<= 1) {
        unsigned add = (t >= o) ? sdata[t - o] : 0u;
        __syncthreads();
        sdata[t] += add;
        __syncthreads();
    }
    unsigned incl = sdata[t];
    unsigned excl = incl - s;
#pragma unroll
    for (int i = 0; i < 4; ++i) {
        int idx = base + i;
        if (idx < n) pre[idx] = excl + v[i];
    }
    if (t == 255) tsums[blockIdx.x] = incl;
}

__global__ __launch_bounds__(256) void scan2_kernel(unsigned* __restrict__ tsums, int nt) {
    __shared__ unsigned sdata[256];
    int t = threadIdx.x;
    unsigned s = (t < nt) ? tsums[t] : 0u;
    sdata[t] = s;
    __syncthreads();
    for (int o = 1; o < 256; o <<= 1) {
        unsigned add = (t >= o) ? sdata[t - o] : 0u;
        __syncthreads();
        sdata[t] += add;
        __syncthreads();
    }
    if (t < nt) tsums[t] = sdata[t] - s;  // exclusive
}

__global__ __launch_bounds__(256) void scan3_kernel(unsigned* __restrict__ row_start,
                                                    const unsigned* __restrict__ tsums,
                                                    unsigned* __restrict__ cursor,
                                                    const unsigned* __restrict__ cnt_in,
                                                    const unsigned* __restrict__ cnt_out,
                                                    float* __restrict__ dsin,
                                                    float* __restrict__ dsout, int n) {
    int i = blockIdx.x * 256 + threadIdx.x;
    if (i < n) {
        unsigned v = row_start[i] + tsums[i >> 10];
        row_start[i] = v;
        cursor[i] = v;
        unsigned ci = cnt_in[i]; if (ci < 1u) ci = 1u;
        unsigned co = cnt_out[i]; if (co < 1u) co = 1u;
        dsin[i] = rsqrtf((float)ci);
        dsout[i] = rsqrtf((float)co);
    }
    if (i == 0) row_start[n] = (unsigned)NE;
}

__global__ __launch_bounds__(256) void fill_kernel(const int* __restrict__ src,
                                                   const int* __restrict__ dst,
                                                   unsigned* __restrict__ cursor,
                                                   int* __restrict__ csr) {
    int e = blockIdx.x * 256 + threadIdx.x;
    if (e < NE) {
        int d = dst[e];
        unsigned pos = atomicAdd(&cursor[d], 1u);
        csr[pos] = src[e];
    }
}

// ---------------- weight prep: transpose + bf16 ----------------
__global__ __launch_bounds__(256) void prep_w_kernel(const float* __restrict__ W1,
                                                     const float* __restrict__ W2,
                                                     unsigned short* __restrict__ W1t,
                                                     unsigned short* __restrict__ W2t) {
    int i = blockIdx.x * 256 + threadIdx.x;
    if (i < HID_DIM * IN_DIM) {  // 32768: W1t[n][k] = W1[k][n]
        int n = i >> 8, k = i & 255;
        W1t[i] = f2bf(W1[k * HID_DIM + n]);
    } else if (i < HID_DIM * IN_DIM + OUT_DIM * HID_DIM) {  // 8192: W2t[n][k] = W2[k][n]
        int m = i - HID_DIM * IN_DIM;
        int n = m >> 7, k = m & 127;
        W2t[m] = f2bf(W2[k * OUT_DIM + n]);
    }
}

// ---------------- GEMM1 (MFMA bf16): feat1[M,128] = (h .* dsout) @ W1 ----------------
// A: h fp32 [M,256] (scaled, converted during staging); B: W1t bf16 [128][256]
__global__ __launch_bounds__(256) void gemm1_kernel(const float* __restrict__ h,
                                                    const unsigned short* __restrict__ W1t,
                                                    const float* __restrict__ dsout,
                                                    unsigned short* __restrict__ feat1, int M) {
    __shared__ unsigned short sA[128][56];  // 112B row: 16B aligned, banks spread
    __shared__ unsigned short sB[128][56];
    const int tid = threadIdx.x;
    const int lane = tid & 63;
    const int wave = tid >> 6;
    const int wm = wave >> 1, wn = wave & 1;
    const int m0 = blockIdx.x * 128;

    f4v acc[4][4];
#pragma unroll
    for (int i = 0; i < 4; ++i)
#pragma unroll
        for (int j = 0; j < 4; ++j) acc[i][j] = (f4v)0.f;

    // hoist per-row dsout for the 4 A rows this thread stages
    const int arow = tid >> 3;          // 0..31
    const int akq = tid & 7;            // float4 within 32-k
    float sc[4];
#pragma unroll
    for (int i = 0; i < 4; ++i) {
        int m = m0 + arow + i * 32;
        sc[i] = (m < M) ? dsout[m] : 0.f;
    }

    for (int k0 = 0; k0 < IN_DIM; k0 += 32) {
        // stage A: 128 rows x 32 k, fp32 -> bf16 scaled
#pragma unroll
        for (int i = 0; i < 4; ++i) {
            int row = arow + i * 32;
            int m = m0 + row;
            float4 v = make_float4(0.f, 0.f, 0.f, 0.f);
            if (m < M) v = *reinterpret_cast<const float4*>(&h[(size_t)m * IN_DIM + k0 + akq * 4]);
            u16x4 p;
            p[0] = f2bf(v.x * sc[i]);
            p[1] = f2bf(v.y * sc[i]);
            p[2] = f2bf(v.z * sc[i]);
            p[3] = f2bf(v.w * sc[i]);
            *reinterpret_cast<u16x4*>(&sA[row][akq * 4]) = p;
        }
        // stage B: 128 n x 32 k bf16 (16B chunks)
#pragma unroll
        for (int i = 0; i < 2; ++i) {
            int idx = tid + i * 256;
            int row = idx >> 2, kq = idx & 3;
            u16x8 w = *reinterpret_cast<const u16x8*>(&W1t[(size_t)row * IN_DIM + k0 + kq * 8]);
            *reinterpret_cast<u16x8*>(&sB[row][kq * 8]) = w;
        }
        __syncthreads();
        s8v a[4];
#pragma unroll
        for (int mi = 0; mi < 4; ++mi)
            a[mi] = *reinterpret_cast<const s8v*>(&sA[wm * 64 + mi * 16 + (lane & 15)][(lane >> 4) * 8]);
#pragma unroll
        for (int ni = 0; ni < 4; ++ni) {
            s8v b = *reinterpret_cast<const s8v*>(&sB[wn * 64 + ni * 16 + (lane & 15)][(lane >> 4) * 8]);
#pragma unroll
            for (int mi = 0; mi < 4; ++mi)
                acc[mi][ni] = __builtin_amdgcn_mfma_f32_16x16x32_bf16(a[mi], b, acc[mi][ni], 0, 0, 0);
        }
        __syncthreads();
    }
#pragma unroll
    for (int mi = 0; mi < 4; ++mi)
#pragma unroll
        for (int ni = 0; ni < 4; ++ni) {
            int col = wn * 64 + ni * 16 + (lane & 15);
#pragma unroll
            for (int j = 0; j < 4; ++j) {
                int row = m0 + wm * 64 + mi * 16 + (lane >> 4) * 4 + j;
                if (row < M) feat1[(size_t)row * HID_DIM + col] = f2bf(acc[mi][ni][j]);
            }
        }
}

// ---------------- GEMM2 (MFMA bf16): feat2[M,64] = xs @ W2 ----------------
__global__ __launch_bounds__(256) void gemm2_kernel(const unsigned short* __restrict__ xs,
                                                    const unsigned short* __restrict__ W2t,
                                                    unsigned short* __restrict__ feat2, int M) {
    __shared__ unsigned short sA[128][56];
    __shared__ unsigned short sB[64][56];
    const int tid = threadIdx.x;
    const int lane = tid & 63;
    const int wave = tid >> 6;
    const int wm = wave >> 1, wn = wave & 1;  // wave tile 64x32
    const int m0 = blockIdx.x * 128;

    f4v acc[4][2];
#pragma unroll
    for (int i = 0; i < 4; ++i)
#pragma unroll
        for (int j = 0; j < 2; ++j) acc[i][j] = (f4v)0.f;

    for (int k0 = 0; k0 < HID_DIM; k0 += 32) {
        // stage A: 128 rows x 32 k bf16 (16B chunks)
#pragma unroll
        for (int i = 0; i < 2; ++i) {
            int idx = tid + i * 256;
            int row = idx >> 2, kq = idx & 3;
            int m = m0 + row;
            u16x8 w = (u16x8)0;
            if (m < M) w = *reinterpret_cast<const u16x8*>(&xs[(size_t)m * HID_DIM + k0 + kq * 8]);
            *reinterpret_cast<u16x8*>(&sA[row][kq * 8]) = w;
        }
        // stage B: 64 n x 32 k
        {
            int row = tid >> 2, kq = tid & 3;
            u16x8 w = *reinterpret_cast<const u16x8*>(&W2t[(size_t)row * HID_DIM + k0 + kq * 8]);
            *reinterpret_cast<u16x8*>(&sB[row][kq * 8]) = w;
        }
        __syncthreads();
        s8v a[4];
#pragma unroll
        for (int mi = 0; mi < 4; ++mi)
            a[mi] = *reinterpret_cast<const s8v*>(&sA[wm * 64 + mi * 16 + (lane & 15)][(lane >> 4) * 8]);
#pragma unroll
        for (int ni = 0; ni < 2; ++ni) {
            s8v b = *reinterpret_cast<const s8v*>(&sB[wn * 32 + ni * 16 + (lane & 15)][(lane >> 4) * 8]);
#pragma unroll
            for (int mi = 0; mi < 4; ++mi)
                acc[mi][ni] = __builtin_amdgcn_mfma_f32_16x16x32_bf16(a[mi], b, acc[mi][ni], 0, 0, 0);
        }
        __syncthreads();
    }
#pragma unroll
    for (int mi = 0; mi < 4; ++mi)
#pragma unroll
        for (int ni = 0; ni < 2; ++ni) {
            int col = wn * 32 + ni * 16 + (lane & 15);
#pragma unroll
            for (int j = 0; j < 4; ++j) {
                int row = m0 + wm * 64 + mi * 16 + (lane >> 4) * 4 + j;
                if (row < M) feat2[(size_t)row * OUT_DIM + col] = f2bf(acc[mi][ni][j]);
            }
        }
}

// ---------------- SpMM layer 1 (bf16 gather) ----------------
__global__ __launch_bounds__(256) void spmm1_kernel(const unsigned short* __restrict__ feat,
                                                    const int* __restrict__ csr,
                                                    const unsigned* __restrict__ rs,
                                                    const float* __restrict__ dsin,
                                                    const float* __restrict__ dsout,
                                                    const float* __restrict__ b1,
                                                    unsigned short* __restrict__ xs) {
    int wave = threadIdx.x >> 6;
    int lane = threadIdx.x & 63;
    int node = blockIdx.x * 4 + wave;
    if (node >= NN) return;
    unsigned s0 = rs[node], s1 = rs[node + 1];
    int c = lane * 2;
    float ax = 0.f, ay = 0.f;
    unsigned j = s0;
    for (; j + 2 <= s1; j += 2) {
        int sa = csr[j], sb = csr[j + 1];
        unsigned va = *reinterpret_cast<const unsigned*>(&feat[(size_t)sa * HID_DIM + c]);
        unsigned vb = *reinterpret_cast<const unsigned*>(&feat[(size_t)sb * HID_DIM + c]);
        ax += bf2f((unsigned short)(va & 0xffff)) + bf2f((unsigned short)(vb & 0xffff));
        ay += bf2f((unsigned short)(va >> 16)) + bf2f((unsigned short)(vb >> 16));
    }
    if (j < s1) {
        int sa = csr[j];
        unsigned va = *reinterpret_cast<const unsigned*>(&feat[(size_t)sa * HID_DIM + c]);
        ax += bf2f((unsigned short)(va & 0xffff));
        ay += bf2f((unsigned short)(va >> 16));
    }
    float si = dsin[node], so = dsout[node];
    float x0 = fmaxf(ax * si + b1[c], 0.f) * so;
    float x1 = fmaxf(ay * si + b1[c + 1], 0.f) * so;
    unsigned p = ((unsigned)f2bf(x1) << 16) | (unsigned)f2bf(x0);
    *reinterpret_cast<unsigned*>(&xs[(size_t)node * HID_DIM + c]) = p;
}

// ---------------- SpMM layer 2 + bias + softmax ----------------
__global__ __launch_bounds__(256) void spmm2_kernel(const unsigned short* __restrict__ feat2,
                                                    const int* __restrict__ csr,
                                                    const unsigned* __restrict__ rs,
                                                    const float* __restrict__ dsin,
                                                    const float* __restrict__ b2,
                                                    float* __restrict__ out) {
    int wave = threadIdx.x >> 6;
    int lane = threadIdx.x & 63;
    int node = blockIdx.x * 4 + wave;
    if (node >= NN) return;
    unsigned s0 = rs[node], s1 = rs[node + 1];
    float acc = 0.f;
    unsigned j = s0;
    for (; j + 2 <= s1; j += 2) {
        int sa = csr[j], sb = csr[j + 1];
        acc += bf2f(feat2[(size_t)sa * OUT_DIM + lane]) + bf2f(feat2[(size_t)sb * OUT_DIM + lane]);
    }
    if (j < s1) acc += bf2f(feat2[(size_t)csr[j] * OUT_DIM + lane]);
    float logit = acc * dsin[node] + b2[lane];
    float m = logit;
    for (int o = 32; o > 0; o >>= 1) m = fmaxf(m, __shfl_xor(m, o, 64));
    float e = __expf(logit - m);
    float sum = e;
    for (int o = 32; o > 0; o >>= 1) sum += __shfl_xor(sum, o, 64);
    float p = e / sum;
    out[(size_t)node * OUT_DIM + lane] = p;
    out[(size_t)NN * OUT_DIM + (size_t)node * OUT_DIM + lane] = logit;
}

static inline size_t align_up(size_t x, size_t a) { return (x + a - 1) & ~(a - 1); }

extern "C" void kernel_launch(void* const* d_in, const int* in_sizes, int n_in,
                              void* d_out, int out_size, void* d_ws, size_t ws_size,
                              hipStream_t stream) {
    (void)in_sizes; (void)n_in; (void)out_size;
    const float* h = (const float*)d_in[0];
    const float* W1 = (const float*)d_in[1];
    const float* b1 = (const float*)d_in[2];
    const float* W2 = (const float*)d_in[3];
    const float* b2 = (const float*)d_in[4];
    const int* src = (const int*)d_in[5];
    const int* dst = (const int*)d_in[6];
    float* out = (float*)d_out;

    char* ws = (char*)d_ws;
    size_t off = 0;
    auto alloc = [&](size_t bytes) {
        void* p = (void*)(ws + off);
        off = align_up(off + bytes, 512);
        return p;
    };
    unsigned* cnt_out = (unsigned*)alloc(NN * 4);
    unsigned* cnt_in = (unsigned*)alloc(NN * 4);
    unsigned* row_start = (unsigned*)alloc((NN + 1) * 4);
    unsigned* cursor = (unsigned*)alloc(NN * 4);
    unsigned* tsums = (unsigned*)alloc(256 * 4);
    float* dsout = (float*)alloc(NN * 4);
    float* dsin = (float*)alloc(NN * 4);
    int* csr = (int*)alloc((size_t)NE * 4);
    unsigned short* W1t = (unsigned short*)alloc((size_t)HID_DIM * IN_DIM * 2);
    unsigned short* W2t = (unsigned short*)alloc((size_t)OUT_DIM * HID_DIM * 2);
    unsigned short* feat1 = (unsigned short*)alloc((size_t)NN * HID_DIM * 2);
    unsigned short* xs = (unsigned short*)alloc((size_t)NN * HID_DIM * 2);
    unsigned short* feat2 = feat1;  // alias: feat1 dead after spmm1

    if (off > ws_size) {
        fprintf(stderr, "kernel_launch: ws too small: need %zu, have %zu\n", off, ws_size);
        return;
    }

    hipMemsetAsync(cnt_out, 0, NN * 4, stream);
    hipMemsetAsync(cnt_in, 0, NN * 4, stream);

    prep_w_kernel<<<(HID_DIM * IN_DIM + OUT_DIM * HID_DIM + 255) / 256, 256, 0, stream>>>(
        W1, W2, W1t, W2t);

    deg_kernel<<<NE / 256, 256, 0, stream>>>(src, dst, cnt_out, cnt_in);

    const int tiles = (NN + 1023) / 1024;  // 98
    scan1_kernel<<<tiles, 256, 0, stream>>>(cnt_in, row_start, tsums, NN);
    scan2_kernel<<<1, 256, 0, stream>>>(tsums, tiles);
    scan3_kernel<<<(NN + 255) / 256, 256, 0, stream>>>(row_start, tsums, cursor, cnt_in,
                                                       cnt_out, dsin, dsout, NN);
    fill_kernel<<<NE / 256, 256, 0, stream>>>(src, dst, cursor, csr);

    gemm1_kernel<<<(NN + 127) / 128, 256, 0, stream>>>(h, W1t, dsout, feat1, NN);
    spmm1_kernel<<<(NN + 3) / 4, 256, 0, stream>>>(feat1, csr, row_start, dsin, dsout, b1, xs);
    gemm2_kernel<<<(NN + 127) / 128, 256, 0, stream>>>(xs, W2t, feat2, NN);
    spmm2_kernel<<<(NN + 3) / 4, 256, 0, stream>>>(feat2, csr, row_start, dsin, b2, out);
}

// Round 3
// 371.002 us; speedup vs baseline: 1.8976x; 1.3884x over previous
//
#include <hip/hip_runtime.h>
#include <cstdio>

#define NN 100000
#define NE 1600000
#define IN_DIM 256
#define HID_DIM 128
#define OUT_DIM 64

#define BSH 7
#define BNODES 128           // nodes per bucket
#define NB 782               // ceil(NN / 128)

typedef short s8v __attribute__((ext_vector_type(8)));
typedef float f4v __attribute__((ext_vector_type(4)));
typedef unsigned short u16x4 __attribute__((ext_vector_type(4)));
typedef unsigned short u16x8 __attribute__((ext_vector_type(8)));

__device__ __forceinline__ unsigned short f2bf(float f) {
    unsigned u = __builtin_bit_cast(unsigned, f);
    u += 0x7FFFu + ((u >> 16) & 1u);  // RNE
    return (unsigned short)(u >> 16);
}
__device__ __forceinline__ float bf2f(unsigned short s) {
    unsigned u = ((unsigned)s) << 16;
    return __builtin_bit_cast(float, u);
}

// ---------------- pass 1: bucket histogram (dst>>7) + out-degree atomics ----------------
#define EPB_H 4096
__global__ __launch_bounds__(256) void histo_kernel(const int* __restrict__ src,
                                                    const int* __restrict__ dst,
                                                    unsigned* __restrict__ cnt_out,
                                                    unsigned* __restrict__ bcnt) {
    __shared__ unsigned hb[NB];
    for (int i = threadIdx.x; i < NB; i += 256) hb[i] = 0u;
    __syncthreads();
    int base = blockIdx.x * EPB_H;
    int n = NE - base; if (n > EPB_H) n = EPB_H;
    for (int i = threadIdx.x; i < n; i += 256) {
        int d = dst[base + i];
        atomicAdd(&hb[d >> BSH], 1u);
        atomicAdd(&cnt_out[src[base + i]], 1u);
    }
    __syncthreads();
    for (int i = threadIdx.x; i < NB; i += 256) {
        unsigned v = hb[i];
        if (v) atomicAdd(&bcnt[i], v);
    }
}

// ---------------- pass 2: scan 782 bucket counts ----------------
__global__ __launch_bounds__(256) void bscan_kernel(const unsigned* __restrict__ bcnt,
                                                    unsigned* __restrict__ bbase,
                                                    unsigned* __restrict__ bcursor) {
    __shared__ unsigned sd[256];
    int t = threadIdx.x;
    unsigned v[4];
    unsigned s = 0;
#pragma unroll
    for (int i = 0; i < 4; ++i) {
        int idx = t * 4 + i;
        unsigned x = (idx < NB) ? bcnt[idx] : 0u;
        v[i] = s;
        s += x;
    }
    sd[t] = s;
    __syncthreads();
    for (int o = 1; o < 256; o <<= 1) {
        unsigned add = (t >= o) ? sd[t - o] : 0u;
        __syncthreads();
        sd[t] += add;
        __syncthreads();
    }
    unsigned incl = sd[t];
    unsigned excl = incl - s;
#pragma unroll
    for (int i = 0; i < 4; ++i) {
        int idx = t * 4 + i;
        if (idx < NB) {
            bbase[idx] = excl + v[i];
            bcursor[idx] = excl + v[i];
        }
    }
    if (t == 255) bbase[NB] = incl;  // == NE
}

// ---------------- pass 3: scatter edges into bucket regions ----------------
#define EPB_S 8192
__global__ __launch_bounds__(256) void bscatter_kernel(const int* __restrict__ src,
                                                       const int* __restrict__ dst,
                                                       unsigned* __restrict__ bcursor,
                                                       unsigned* __restrict__ ebuf) {
    __shared__ unsigned hb[NB];
    for (int i = threadIdx.x; i < NB; i += 256) hb[i] = 0u;
    __syncthreads();
    int base = blockIdx.x * EPB_S;
    int n = NE - base; if (n > EPB_S) n = EPB_S;
    for (int i = threadIdx.x; i < n; i += 256) atomicAdd(&hb[dst[base + i] >> BSH], 1u);
    __syncthreads();
    // reserve contiguous sub-range per (block,bucket)
    for (int i = threadIdx.x; i < NB; i += 256) {
        unsigned c = hb[i];
        hb[i] = c ? atomicAdd(&bcursor[i], c) : 0u;
    }
    __syncthreads();
    for (int i = threadIdx.x; i < n; i += 256) {
        int d = dst[base + i];
        int s = src[base + i];
        unsigned pos = atomicAdd(&hb[d >> BSH], 1u);
        ebuf[pos] = ((unsigned)(d & (BNODES - 1)) << 20) | (unsigned)s;
    }
}

// ---------------- pass 4: per-bucket counting sort -> CSR + row_start + dsin ----------------
__global__ __launch_bounds__(256) void bsort_kernel(const unsigned* __restrict__ ebuf,
                                                    const unsigned* __restrict__ bbase,
                                                    int* __restrict__ csr,
                                                    unsigned* __restrict__ row_start,
                                                    float* __restrict__ dsin) {
    __shared__ unsigned hn[BNODES];
    __shared__ unsigned sc[BNODES];
    __shared__ unsigned cur[BNODES];
    int b = blockIdx.x;
    int t = threadIdx.x;
    unsigned e0 = bbase[b], e1 = bbase[b + 1];
    if (t < BNODES) hn[t] = 0u;
    __syncthreads();
    for (unsigned j = e0 + t; j < e1; j += 256) atomicAdd(&hn[(ebuf[j] >> 20) & (BNODES - 1)], 1u);
    __syncthreads();
    unsigned cnt_t = (t < BNODES) ? hn[t] : 0u;
    if (t < BNODES) sc[t] = cnt_t;
    __syncthreads();
    for (int o = 1; o < BNODES; o <<= 1) {
        unsigned add = (t < BNODES && t >= o) ? sc[t - o] : 0u;
        __syncthreads();
        if (t < BNODES) sc[t] += add;
        __syncthreads();
    }
    if (t < BNODES) {
        unsigned excl = sc[t] - cnt_t;
        cur[t] = e0 + excl;
        int node = (b << BSH) + t;
        if (node < NN) {
            row_start[node] = e0 + excl;
            dsin[node] = rsqrtf((float)(cnt_t ? cnt_t : 1u));
        }
    }
    __syncthreads();
    for (unsigned j = e0 + t; j < e1; j += 256) {
        unsigned pk = ebuf[j];
        unsigned pos = atomicAdd(&cur[(pk >> 20) & (BNODES - 1)], 1u);
        csr[pos] = (int)(pk & 0xFFFFFu);
    }
    if (b == 0 && t == 0) row_start[NN] = (unsigned)NE;
}

// ---------------- weight prep: transpose + bf16 ----------------
__global__ __launch_bounds__(256) void prep_w_kernel(const float* __restrict__ W1,
                                                     const float* __restrict__ W2,
                                                     unsigned short* __restrict__ W1t,
                                                     unsigned short* __restrict__ W2t) {
    int i = blockIdx.x * 256 + threadIdx.x;
    if (i < HID_DIM * IN_DIM) {  // W1t[n][k] = W1[k][n]
        int n = i >> 8, k = i & 255;
        W1t[i] = f2bf(W1[k * HID_DIM + n]);
    } else if (i < HID_DIM * IN_DIM + OUT_DIM * HID_DIM) {  // W2t[n][k] = W2[k][n]
        int m = i - HID_DIM * IN_DIM;
        int n = m >> 7, k = m & 127;
        W2t[m] = f2bf(W2[k * OUT_DIM + n]);
    }
}

// ---------------- GEMM1 (MFMA bf16): feat1[M,128] = (h .* dsout) @ W1 ----------------
__global__ __launch_bounds__(256) void gemm1_kernel(const float* __restrict__ h,
                                                    const unsigned short* __restrict__ W1t,
                                                    const unsigned* __restrict__ cnt_out,
                                                    unsigned short* __restrict__ feat1, int M) {
    __shared__ unsigned short sA[128][56];
    __shared__ unsigned short sB[128][56];
    const int tid = threadIdx.x;
    const int lane = tid & 63;
    const int wave = tid >> 6;
    const int wm = wave >> 1, wn = wave & 1;
    const int m0 = blockIdx.x * 128;

    f4v acc[4][4];
#pragma unroll
    for (int i = 0; i < 4; ++i)
#pragma unroll
        for (int j = 0; j < 4; ++j) acc[i][j] = (f4v)0.f;

    const int arow = tid >> 3;
    const int akq = tid & 7;
    float sc[4];
#pragma unroll
    for (int i = 0; i < 4; ++i) {
        int m = m0 + arow + i * 32;
        if (m < M) {
            unsigned c = cnt_out[m];
            sc[i] = rsqrtf((float)(c ? c : 1u));
        } else sc[i] = 0.f;
    }

    for (int k0 = 0; k0 < IN_DIM; k0 += 32) {
#pragma unroll
        for (int i = 0; i < 4; ++i) {
            int row = arow + i * 32;
            int m = m0 + row;
            float4 v = make_float4(0.f, 0.f, 0.f, 0.f);
            if (m < M) v = *reinterpret_cast<const float4*>(&h[(size_t)m * IN_DIM + k0 + akq * 4]);
            u16x4 p;
            p[0] = f2bf(v.x * sc[i]);
            p[1] = f2bf(v.y * sc[i]);
            p[2] = f2bf(v.z * sc[i]);
            p[3] = f2bf(v.w * sc[i]);
            *reinterpret_cast<u16x4*>(&sA[row][akq * 4]) = p;
        }
#pragma unroll
        for (int i = 0; i < 2; ++i) {
            int idx = tid + i * 256;
            int row = idx >> 2, kq = idx & 3;
            u16x8 w = *reinterpret_cast<const u16x8*>(&W1t[(size_t)row * IN_DIM + k0 + kq * 8]);
            *reinterpret_cast<u16x8*>(&sB[row][kq * 8]) = w;
        }
        __syncthreads();
        s8v a[4];
#pragma unroll
        for (int mi = 0; mi < 4; ++mi)
            a[mi] = *reinterpret_cast<const s8v*>(&sA[wm * 64 + mi * 16 + (lane & 15)][(lane >> 4) * 8]);
#pragma unroll
        for (int ni = 0; ni < 4; ++ni) {
            s8v b = *reinterpret_cast<const s8v*>(&sB[wn * 64 + ni * 16 + (lane & 15)][(lane >> 4) * 8]);
#pragma unroll
            for (int mi = 0; mi < 4; ++mi)
                acc[mi][ni] = __builtin_amdgcn_mfma_f32_16x16x32_bf16(a[mi], b, acc[mi][ni], 0, 0, 0);
        }
        __syncthreads();
    }
#pragma unroll
    for (int mi = 0; mi < 4; ++mi)
#pragma unroll
        for (int ni = 0; ni < 4; ++ni) {
            int col = wn * 64 + ni * 16 + (lane & 15);
#pragma unroll
            for (int j = 0; j < 4; ++j) {
                int row = m0 + wm * 64 + mi * 16 + (lane >> 4) * 4 + j;
                if (row < M) feat1[(size_t)row * HID_DIM + col] = f2bf(acc[mi][ni][j]);
            }
        }
}

// ---------------- GEMM2 (MFMA bf16): feat2[M,64] = xs @ W2 ----------------
__global__ __launch_bounds__(256) void gemm2_kernel(const unsigned short* __restrict__ xs,
                                                    const unsigned short* __restrict__ W2t,
                                                    unsigned short* __restrict__ feat2, int M) {
    __shared__ unsigned short sA[128][56];
    __shared__ unsigned short sB[64][56];
    const int tid = threadIdx.x;
    const int lane = tid & 63;
    const int wave = tid >> 6;
    const int wm = wave >> 1, wn = wave & 1;
    const int m0 = blockIdx.x * 128;

    f4v acc[4][2];
#pragma unroll
    for (int i = 0; i < 4; ++i)
#pragma unroll
        for (int j = 0; j < 2; ++j) acc[i][j] = (f4v)0.f;

    for (int k0 = 0; k0 < HID_DIM; k0 += 32) {
#pragma unroll
        for (int i = 0; i < 2; ++i) {
            int idx = tid + i * 256;
            int row = idx >> 2, kq = idx & 3;
            int m = m0 + row;
            u16x8 w = (u16x8)0;
            if (m < M) w = *reinterpret_cast<const u16x8*>(&xs[(size_t)m * HID_DIM + k0 + kq * 8]);
            *reinterpret_cast<u16x8*>(&sA[row][kq * 8]) = w;
        }
        {
            int row = tid >> 2, kq = tid & 3;
            u16x8 w = *reinterpret_cast<const u16x8*>(&W2t[(size_t)row * HID_DIM + k0 + kq * 8]);
            *reinterpret_cast<u16x8*>(&sB[row][kq * 8]) = w;
        }
        __syncthreads();
        s8v a[4];
#pragma unroll
        for (int mi = 0; mi < 4; ++mi)
            a[mi] = *reinterpret_cast<const s8v*>(&sA[wm * 64 + mi * 16 + (lane & 15)][(lane >> 4) * 8]);
#pragma unroll
        for (int ni = 0; ni < 2; ++ni) {
            s8v b = *reinterpret_cast<const s8v*>(&sB[wn * 32 + ni * 16 + (lane & 15)][(lane >> 4) * 8]);
#pragma unroll
            for (int mi = 0; mi < 4; ++mi)
                acc[mi][ni] = __builtin_amdgcn_mfma_f32_16x16x32_bf16(a[mi], b, acc[mi][ni], 0, 0, 0);
        }
        __syncthreads();
    }
#pragma unroll
    for (int mi = 0; mi < 4; ++mi)
#pragma unroll
        for (int ni = 0; ni < 2; ++ni) {
            int col = wn * 32 + ni * 16 + (lane & 15);
#pragma unroll
            for (int j = 0; j < 4; ++j) {
                int row = m0 + wm * 64 + mi * 16 + (lane >> 4) * 4 + j;
                if (row < M) feat2[(size_t)row * OUT_DIM + col] = f2bf(acc[mi][ni][j]);
            }
        }
}

// ---------------- SpMM layer 1 (bf16 gather) ----------------
__global__ __launch_bounds__(256) void spmm1_kernel(const unsigned short* __restrict__ feat,
                                                    const int* __restrict__ csr,
                                                    const unsigned* __restrict__ rs,
                                                    const float* __restrict__ dsin,
                                                    const unsigned* __restrict__ cnt_out,
                                                    const float* __restrict__ b1,
                                                    unsigned short* __restrict__ xs) {
    int wave = threadIdx.x >> 6;
    int lane = threadIdx.x & 63;
    int node = blockIdx.x * 4 + wave;
    if (node >= NN) return;
    unsigned s0 = rs[node], s1 = rs[node + 1];
    int c = lane * 2;
    float ax = 0.f, ay = 0.f;
    unsigned j = s0;
    for (; j + 2 <= s1; j += 2) {
        int sa = csr[j], sb = csr[j + 1];
        unsigned va = *reinterpret_cast<const unsigned*>(&feat[(size_t)sa * HID_DIM + c]);
        unsigned vb = *reinterpret_cast<const unsigned*>(&feat[(size_t)sb * HID_DIM + c]);
        ax += bf2f((unsigned short)(va & 0xffff)) + bf2f((unsigned short)(vb & 0xffff));
        ay += bf2f((unsigned short)(va >> 16)) + bf2f((unsigned short)(vb >> 16));
    }
    if (j < s1) {
        int sa = csr[j];
        unsigned va = *reinterpret_cast<const unsigned*>(&feat[(size_t)sa * HID_DIM + c]);
        ax += bf2f((unsigned short)(va & 0xffff));
        ay += bf2f((unsigned short)(va >> 16));
    }
    float si = dsin[node];
    unsigned co = cnt_out[node];
    float so = rsqrtf((float)(co ? co : 1u));
    float x0 = fmaxf(ax * si + b1[c], 0.f) * so;
    float x1 = fmaxf(ay * si + b1[c + 1], 0.f) * so;
    unsigned p = ((unsigned)f2bf(x1) << 16) | (unsigned)f2bf(x0);
    *reinterpret_cast<unsigned*>(&xs[(size_t)node * HID_DIM + c]) = p;
}

// ---------------- SpMM layer 2 + bias + softmax ----------------
__global__ __launch_bounds__(256) void spmm2_kernel(const unsigned short* __restrict__ feat2,
                                                    const int* __restrict__ csr,
                                                    const unsigned* __restrict__ rs,
                                                    const float* __restrict__ dsin,
                                                    const float* __restrict__ b2,
                                                    float* __restrict__ out) {
    int wave = threadIdx.x >> 6;
    int lane = threadIdx.x & 63;
    int node = blockIdx.x * 4 + wave;
    if (node >= NN) return;
    unsigned s0 = rs[node], s1 = rs[node + 1];
    float acc = 0.f;
    unsigned j = s0;
    for (; j + 2 <= s1; j += 2) {
        int sa = csr[j], sb = csr[j + 1];
        acc += bf2f(feat2[(size_t)sa * OUT_DIM + lane]) + bf2f(feat2[(size_t)sb * OUT_DIM + lane]);
    }
    if (j < s1) acc += bf2f(feat2[(size_t)csr[j] * OUT_DIM + lane]);
    float logit = acc * dsin[node] + b2[lane];
    float m = logit;
    for (int o = 32; o > 0; o >>= 1) m = fmaxf(m, __shfl_xor(m, o, 64));
    float e = __expf(logit - m);
    float sum = e;
    for (int o = 32; o > 0; o >>= 1) sum += __shfl_xor(sum, o, 64);
    float p = e / sum;
    out[(size_t)node * OUT_DIM + lane] = p;
    out[(size_t)NN * OUT_DIM + (size_t)node * OUT_DIM + lane] = logit;
}

static inline size_t align_up(size_t x, size_t a) { return (x + a - 1) & ~(a - 1); }

extern "C" void kernel_launch(void* const* d_in, const int* in_sizes, int n_in,
                              void* d_out, int out_size, void* d_ws, size_t ws_size,
                              hipStream_t stream) {
    (void)in_sizes; (void)n_in; (void)out_size;
    const float* h = (const float*)d_in[0];
    const float* W1 = (const float*)d_in[1];
    const float* b1 = (const float*)d_in[2];
    const float* W2 = (const float*)d_in[3];
    const float* b2 = (const float*)d_in[4];
    const int* src = (const int*)d_in[5];
    const int* dst = (const int*)d_in[6];
    float* out = (float*)d_out;

    char* ws = (char*)d_ws;
    size_t off = 0;
    auto alloc = [&](size_t bytes) {
        void* p = (void*)(ws + off);
        off = align_up(off + bytes, 512);
        return p;
    };
    unsigned* cnt_out = (unsigned*)alloc(NN * 4);
    unsigned* bcnt = (unsigned*)alloc(NB * 4);
    unsigned* bbase = (unsigned*)alloc((NB + 1) * 4);
    unsigned* bcursor = (unsigned*)alloc(NB * 4);
    unsigned* row_start = (unsigned*)alloc((NN + 1) * 4);
    float* dsin = (float*)alloc(NN * 4);
    unsigned* ebuf = (unsigned*)alloc((size_t)NE * 4);
    int* csr = (int*)alloc((size_t)NE * 4);
    unsigned short* W1t = (unsigned short*)alloc((size_t)HID_DIM * IN_DIM * 2);
    unsigned short* W2t = (unsigned short*)alloc((size_t)OUT_DIM * HID_DIM * 2);
    unsigned short* feat1 = (unsigned short*)alloc((size_t)NN * HID_DIM * 2);
    unsigned short* xs = (unsigned short*)alloc((size_t)NN * HID_DIM * 2);
    unsigned short* feat2 = feat1;  // alias: feat1 dead after spmm1

    if (off > ws_size) {
        fprintf(stderr, "kernel_launch: ws too small: need %zu, have %zu\n", off, ws_size);
        return;
    }

    hipMemsetAsync(cnt_out, 0, NN * 4, stream);
    hipMemsetAsync(bcnt, 0, NB * 4, stream);

    prep_w_kernel<<<(HID_DIM * IN_DIM + OUT_DIM * HID_DIM + 255) / 256, 256, 0, stream>>>(
        W1, W2, W1t, W2t);

    histo_kernel<<<(NE + EPB_H - 1) / EPB_H, 256, 0, stream>>>(src, dst, cnt_out, bcnt);
    bscan_kernel<<<1, 256, 0, stream>>>(bcnt, bbase, bcursor);
    bscatter_kernel<<<(NE + EPB_S - 1) / EPB_S, 256, 0, stream>>>(src, dst, bcursor, ebuf);
    bsort_kernel<<<NB, 256, 0, stream>>>(ebuf, bbase, csr, row_start, dsin);

    gemm1_kernel<<<(NN + 127) / 128, 256, 0, stream>>>(h, W1t, cnt_out, feat1, NN);
    spmm1_kernel<<<(NN + 3) / 4, 256, 0, stream>>>(feat1, csr, row_start, dsin, cnt_out, b1, xs);
    gemm2_kernel<<<(NN + 127) / 128, 256, 0, stream>>>(xs, W2t, feat2, NN);
    spmm2_kernel<<<(NN + 3) / 4, 256, 0, stream>>>(feat2, csr, row_start, dsin, b2, out);
}

// Round 4
// 264.572 us; speedup vs baseline: 2.6610x; 1.4023x over previous
//
#include <hip/hip_runtime.h>
#include <cstdio>

#define NN 100000
#define NE 1600000
#define IN_DIM 256
#define HID_DIM 128
#define OUT_DIM 64

#define BSH 7
#define BNODES 128           // nodes per bucket
#define NB 782               // ceil(NN / 128)
#define CAP 2560             // per-bucket edge capacity (mean 2048, +11 sigma)
#define EPB 4096             // edges per scatter block

typedef short s8v __attribute__((ext_vector_type(8)));
typedef float f4v __attribute__((ext_vector_type(4)));
typedef unsigned short u16x4 __attribute__((ext_vector_type(4)));
typedef unsigned short u16x8 __attribute__((ext_vector_type(8)));

__device__ __forceinline__ unsigned short f2bf(float f) {
    unsigned u = __builtin_bit_cast(unsigned, f);
    u += 0x7FFFu + ((u >> 16) & 1u);  // RNE
    return (unsigned short)(u >> 16);
}
__device__ __forceinline__ float bf2f(unsigned short s) {
    unsigned u = ((unsigned)s) << 16;
    return __builtin_bit_cast(float, u);
}

// ---------------- init: zero cnt_out, set bucket cursors ----------------
__global__ __launch_bounds__(256) void init_kernel(unsigned* __restrict__ cnt_out,
                                                   unsigned* __restrict__ bcursor) {
    int i = blockIdx.x * 256 + threadIdx.x;
    if (i < NN) cnt_out[i] = 0u;
    if (i < NB) bcursor[i] = (unsigned)(i * CAP);
}

// ---------------- single pass over edges: out-degree + bucket scatter ----------------
__global__ __launch_bounds__(256) void scat_kernel(const int* __restrict__ src,
                                                   const int* __restrict__ dst,
                                                   unsigned* __restrict__ cnt_out,
                                                   unsigned* __restrict__ bcursor,
                                                   unsigned* __restrict__ ebuf) {
    __shared__ unsigned hb[NB];
    for (int i = threadIdx.x; i < NB; i += 256) hb[i] = 0u;
    __syncthreads();
    int base = blockIdx.x * EPB;
    int n = NE - base; if (n > EPB) n = EPB;
    for (int i = threadIdx.x; i < n; i += 256) {
        atomicAdd(&hb[dst[base + i] >> BSH], 1u);
        atomicAdd(&cnt_out[src[base + i]], 1u);
    }
    __syncthreads();
    // reserve contiguous sub-range per (block,bucket)
    for (int i = threadIdx.x; i < NB; i += 256) {
        unsigned c = hb[i];
        hb[i] = c ? atomicAdd(&bcursor[i], c) : 0u;
    }
    __syncthreads();
    for (int i = threadIdx.x; i < n; i += 256) {
        int d = dst[base + i];
        int s = src[base + i];
        unsigned pos = atomicAdd(&hb[d >> BSH], 1u);
        ebuf[pos] = ((unsigned)(d & (BNODES - 1)) << 20) | (unsigned)s;
    }
}

// ---------------- per-bucket counting sort -> CSR + rsinfo + dsin ----------------
__global__ __launch_bounds__(256) void bsort_kernel(const unsigned* __restrict__ ebuf,
                                                    const unsigned* __restrict__ bcursor,
                                                    int* __restrict__ csr,
                                                    unsigned* __restrict__ rsinfo,
                                                    float* __restrict__ dsin) {
    __shared__ unsigned hn[BNODES];
    __shared__ unsigned sc[BNODES];
    __shared__ unsigned cur[BNODES];
    int b = blockIdx.x;
    int t = threadIdx.x;
    unsigned e0 = (unsigned)(b * CAP);
    unsigned e1 = bcursor[b];  // end cursor after scatter
    if (t < BNODES) hn[t] = 0u;
    __syncthreads();
    for (unsigned j = e0 + t; j < e1; j += 256) atomicAdd(&hn[(ebuf[j] >> 20) & 127u], 1u);
    __syncthreads();
    unsigned cnt_t = (t < BNODES) ? hn[t] : 0u;
    if (t < BNODES) sc[t] = cnt_t;
    __syncthreads();
    for (int o = 1; o < BNODES; o <<= 1) {
        unsigned add = (t < BNODES && t >= o) ? sc[t - o] : 0u;
        __syncthreads();
        if (t < BNODES) sc[t] += add;
        __syncthreads();
    }
    if (t < BNODES) {
        unsigned excl = sc[t] - cnt_t;
        cur[t] = e0 + excl;
        int node = (b << BSH) + t;
        if (node < NN) {
            rsinfo[node] = ((e0 + excl) << 10) | (cnt_t & 1023u);
            dsin[node] = rsqrtf((float)(cnt_t ? cnt_t : 1u));
        }
    }
    __syncthreads();
    for (unsigned j = e0 + t; j < e1; j += 256) {
        unsigned pk = ebuf[j];
        unsigned pos = atomicAdd(&cur[(pk >> 20) & 127u], 1u);
        csr[pos] = (int)(pk & 0xFFFFFu);
    }
}

// ---------------- weight prep: transpose + bf16 ----------------
__global__ __launch_bounds__(256) void prep_w_kernel(const float* __restrict__ W1,
                                                     const float* __restrict__ W2,
                                                     unsigned short* __restrict__ W1t,
                                                     unsigned short* __restrict__ W2t) {
    int i = blockIdx.x * 256 + threadIdx.x;
    if (i < HID_DIM * IN_DIM) {  // W1t[n][k] = W1[k][n]
        int n = i >> 8, k = i & 255;
        W1t[i] = f2bf(W1[k * HID_DIM + n]);
    } else if (i < HID_DIM * IN_DIM + OUT_DIM * HID_DIM) {  // W2t[n][k] = W2[k][n]
        int m = i - HID_DIM * IN_DIM;
        int n = m >> 7, k = m & 127;
        W2t[m] = f2bf(W2[k * OUT_DIM + n]);
    }
}

// ---------------- GEMM1 (MFMA bf16): feat1[M,128] = (h .* dsout) @ W1 ----------------
__global__ __launch_bounds__(256) void gemm1_kernel(const float* __restrict__ h,
                                                    const unsigned short* __restrict__ W1t,
                                                    const unsigned* __restrict__ cnt_out,
                                                    unsigned short* __restrict__ feat1, int M) {
    __shared__ unsigned short sA[128][56];
    __shared__ unsigned short sB[128][56];
    const int tid = threadIdx.x;
    const int lane = tid & 63;
    const int wave = tid >> 6;
    const int wm = wave >> 1, wn = wave & 1;
    const int m0 = blockIdx.x * 128;

    f4v acc[4][4];
#pragma unroll
    for (int i = 0; i < 4; ++i)
#pragma unroll
        for (int j = 0; j < 4; ++j) acc[i][j] = (f4v)0.f;

    const int arow = tid >> 3;
    const int akq = tid & 7;
    float sc[4];
#pragma unroll
    for (int i = 0; i < 4; ++i) {
        int m = m0 + arow + i * 32;
        if (m < M) {
            unsigned c = cnt_out[m];
            sc[i] = rsqrtf((float)(c ? c : 1u));
        } else sc[i] = 0.f;
    }

    for (int k0 = 0; k0 < IN_DIM; k0 += 32) {
#pragma unroll
        for (int i = 0; i < 4; ++i) {
            int row = arow + i * 32;
            int m = m0 + row;
            float4 v = make_float4(0.f, 0.f, 0.f, 0.f);
            if (m < M) v = *reinterpret_cast<const float4*>(&h[(size_t)m * IN_DIM + k0 + akq * 4]);
            u16x4 p;
            p[0] = f2bf(v.x * sc[i]);
            p[1] = f2bf(v.y * sc[i]);
            p[2] = f2bf(v.z * sc[i]);
            p[3] = f2bf(v.w * sc[i]);
            *reinterpret_cast<u16x4*>(&sA[row][akq * 4]) = p;
        }
#pragma unroll
        for (int i = 0; i < 2; ++i) {
            int idx = tid + i * 256;
            int row = idx >> 2, kq = idx & 3;
            u16x8 w = *reinterpret_cast<const u16x8*>(&W1t[(size_t)row * IN_DIM + k0 + kq * 8]);
            *reinterpret_cast<u16x8*>(&sB[row][kq * 8]) = w;
        }
        __syncthreads();
        s8v a[4];
#pragma unroll
        for (int mi = 0; mi < 4; ++mi)
            a[mi] = *reinterpret_cast<const s8v*>(&sA[wm * 64 + mi * 16 + (lane & 15)][(lane >> 4) * 8]);
#pragma unroll
        for (int ni = 0; ni < 4; ++ni) {
            s8v b = *reinterpret_cast<const s8v*>(&sB[wn * 64 + ni * 16 + (lane & 15)][(lane >> 4) * 8]);
#pragma unroll
            for (int mi = 0; mi < 4; ++mi)
                acc[mi][ni] = __builtin_amdgcn_mfma_f32_16x16x32_bf16(a[mi], b, acc[mi][ni], 0, 0, 0);
        }
        __syncthreads();
    }
#pragma unroll
    for (int mi = 0; mi < 4; ++mi)
#pragma unroll
        for (int ni = 0; ni < 4; ++ni) {
            int col = wn * 64 + ni * 16 + (lane & 15);
#pragma unroll
            for (int j = 0; j < 4; ++j) {
                int row = m0 + wm * 64 + mi * 16 + (lane >> 4) * 4 + j;
                if (row < M) feat1[(size_t)row * HID_DIM + col] = f2bf(acc[mi][ni][j]);
            }
        }
}

// ---------------- GEMM2 (MFMA bf16): feat2[M,64] = xs @ W2 ----------------
__global__ __launch_bounds__(256) void gemm2_kernel(const unsigned short* __restrict__ xs,
                                                    const unsigned short* __restrict__ W2t,
                                                    unsigned short* __restrict__ feat2, int M) {
    __shared__ unsigned short sA[128][56];
    __shared__ unsigned short sB[64][56];
    const int tid = threadIdx.x;
    const int lane = tid & 63;
    const int wave = tid >> 6;
    const int wm = wave >> 1, wn = wave & 1;
    const int m0 = blockIdx.x * 128;

    f4v acc[4][2];
#pragma unroll
    for (int i = 0; i < 4; ++i)
#pragma unroll
        for (int j = 0; j < 2; ++j) acc[i][j] = (f4v)0.f;

    for (int k0 = 0; k0 < HID_DIM; k0 += 32) {
#pragma unroll
        for (int i = 0; i < 2; ++i) {
            int idx = tid + i * 256;
            int row = idx >> 2, kq = idx & 3;
            int m = m0 + row;
            u16x8 w = (u16x8)0;
            if (m < M) w = *reinterpret_cast<const u16x8*>(&xs[(size_t)m * HID_DIM + k0 + kq * 8]);
            *reinterpret_cast<u16x8*>(&sA[row][kq * 8]) = w;
        }
        {
            int row = tid >> 2, kq = tid & 3;
            u16x8 w = *reinterpret_cast<const u16x8*>(&W2t[(size_t)row * HID_DIM + k0 + kq * 8]);
            *reinterpret_cast<u16x8*>(&sB[row][kq * 8]) = w;
        }
        __syncthreads();
        s8v a[4];
#pragma unroll
        for (int mi = 0; mi < 4; ++mi)
            a[mi] = *reinterpret_cast<const s8v*>(&sA[wm * 64 + mi * 16 + (lane & 15)][(lane >> 4) * 8]);
#pragma unroll
        for (int ni = 0; ni < 2; ++ni) {
            s8v b = *reinterpret_cast<const s8v*>(&sB[wn * 32 + ni * 16 + (lane & 15)][(lane >> 4) * 8]);
#pragma unroll
            for (int mi = 0; mi < 4; ++mi)
                acc[mi][ni] = __builtin_amdgcn_mfma_f32_16x16x32_bf16(a[mi], b, acc[mi][ni], 0, 0, 0);
        }
        __syncthreads();
    }
#pragma unroll
    for (int mi = 0; mi < 4; ++mi)
#pragma unroll
        for (int ni = 0; ni < 2; ++ni) {
            int col = wn * 32 + ni * 16 + (lane & 15);
#pragma unroll
            for (int j = 0; j < 4; ++j) {
                int row = m0 + wm * 64 + mi * 16 + (lane >> 4) * 4 + j;
                if (row < M) feat2[(size_t)row * OUT_DIM + col] = f2bf(acc[mi][ni][j]);
            }
        }
}

// ---------------- SpMM layer 1: shfl-broadcast indices, 4 gathers in flight ----------------
__global__ __launch_bounds__(256) void spmm1_kernel(const unsigned short* __restrict__ feat,
                                                    const int* __restrict__ csr,
                                                    const unsigned* __restrict__ rsinfo,
                                                    const float* __restrict__ dsin,
                                                    const unsigned* __restrict__ cnt_out,
                                                    const float* __restrict__ b1,
                                                    unsigned short* __restrict__ xs) {
    int wave = threadIdx.x >> 6;
    int lane = threadIdx.x & 63;
    int node = blockIdx.x * 4 + wave;
    if (node >= NN) return;
    unsigned info = rsinfo[node];
    unsigned j = info >> 10;
    int rem = (int)(info & 1023u);
    int c = lane * 2;
    float ax = 0.f, ay = 0.f;
    while (rem > 0) {
        int take = rem < 64 ? rem : 64;
        int idx = (lane < take) ? csr[j + lane] : 0;
        int e = 0;
        for (; e + 4 <= take; e += 4) {
            int s0 = __shfl(idx, e, 64);
            int s1 = __shfl(idx, e + 1, 64);
            int s2 = __shfl(idx, e + 2, 64);
            int s3 = __shfl(idx, e + 3, 64);
            unsigned v0 = *reinterpret_cast<const unsigned*>(&feat[(size_t)s0 * HID_DIM + c]);
            unsigned v1 = *reinterpret_cast<const unsigned*>(&feat[(size_t)s1 * HID_DIM + c]);
            unsigned v2 = *reinterpret_cast<const unsigned*>(&feat[(size_t)s2 * HID_DIM + c]);
            unsigned v3 = *reinterpret_cast<const unsigned*>(&feat[(size_t)s3 * HID_DIM + c]);
            ax += bf2f((unsigned short)(v0 & 0xffff)) + bf2f((unsigned short)(v1 & 0xffff))
                + bf2f((unsigned short)(v2 & 0xffff)) + bf2f((unsigned short)(v3 & 0xffff));
            ay += bf2f((unsigned short)(v0 >> 16)) + bf2f((unsigned short)(v1 >> 16))
                + bf2f((unsigned short)(v2 >> 16)) + bf2f((unsigned short)(v3 >> 16));
        }
        for (; e < take; ++e) {
            int s0 = __shfl(idx, e, 64);
            unsigned v0 = *reinterpret_cast<const unsigned*>(&feat[(size_t)s0 * HID_DIM + c]);
            ax += bf2f((unsigned short)(v0 & 0xffff));
            ay += bf2f((unsigned short)(v0 >> 16));
        }
        j += take; rem -= take;
    }
    float si = dsin[node];
    unsigned co = cnt_out[node];
    float so = rsqrtf((float)(co ? co : 1u));
    float2 bb = *reinterpret_cast<const float2*>(&b1[c]);
    float x0 = fmaxf(ax * si + bb.x, 0.f) * so;
    float x1 = fmaxf(ay * si + bb.y, 0.f) * so;
    unsigned p = ((unsigned)f2bf(x1) << 16) | (unsigned)f2bf(x0);
    *reinterpret_cast<unsigned*>(&xs[(size_t)node * HID_DIM + c]) = p;
}

// ---------------- SpMM layer 2: 2 edges per load + softmax ----------------
__global__ __launch_bounds__(256) void spmm2_kernel(const unsigned short* __restrict__ feat2,
                                                    const int* __restrict__ csr,
                                                    const unsigned* __restrict__ rsinfo,
                                                    const float* __restrict__ dsin,
                                                    const float* __restrict__ b2,
                                                    float* __restrict__ out) {
    int wave = threadIdx.x >> 6;
    int lane = threadIdx.x & 63;
    int node = blockIdx.x * 4 + wave;
    if (node >= NN) return;
    unsigned info = rsinfo[node];
    unsigned j = info >> 10;
    int rem = (int)(info & 1023u);
    int half = lane >> 5;       // which edge of a pair this lane serves
    int c2 = (lane & 31) * 2;   // column pair
    float a0 = 0.f, a1 = 0.f;
    while (rem > 0) {
        int take = rem < 64 ? rem : 64;
        int idx = (lane < take) ? csr[j + lane] : 0;
        int e = 0;
        for (; e + 8 <= take; e += 8) {
            int sA = __shfl(idx, e + half, 64);
            int sB = __shfl(idx, e + 2 + half, 64);
            int sC = __shfl(idx, e + 4 + half, 64);
            int sD = __shfl(idx, e + 6 + half, 64);
            unsigned vA = *reinterpret_cast<const unsigned*>(&feat2[(size_t)sA * OUT_DIM + c2]);
            unsigned vB = *reinterpret_cast<const unsigned*>(&feat2[(size_t)sB * OUT_DIM + c2]);
            unsigned vC = *reinterpret_cast<const unsigned*>(&feat2[(size_t)sC * OUT_DIM + c2]);
            unsigned vD = *reinterpret_cast<const unsigned*>(&feat2[(size_t)sD * OUT_DIM + c2]);
            a0 += bf2f((unsigned short)(vA & 0xffff)) + bf2f((unsigned short)(vB & 0xffff))
                + bf2f((unsigned short)(vC & 0xffff)) + bf2f((unsigned short)(vD & 0xffff));
            a1 += bf2f((unsigned short)(vA >> 16)) + bf2f((unsigned short)(vB >> 16))
                + bf2f((unsigned short)(vC >> 16)) + bf2f((unsigned short)(vD >> 16));
        }
        for (; e + 2 <= take; e += 2) {
            int sA = __shfl(idx, e + half, 64);
            unsigned vA = *reinterpret_cast<const unsigned*>(&feat2[(size_t)sA * OUT_DIM + c2]);
            a0 += bf2f((unsigned short)(vA & 0xffff));
            a1 += bf2f((unsigned short)(vA >> 16));
        }
        if (e < take) {  // odd leftover: lanes of half==0 only
            int sA = __shfl(idx, e, 64);
            if (half == 0) {
                unsigned vA = *reinterpret_cast<const unsigned*>(&feat2[(size_t)sA * OUT_DIM + c2]);
                a0 += bf2f((unsigned short)(vA & 0xffff));
                a1 += bf2f((unsigned short)(vA >> 16));
            }
        }
        j += take; rem -= take;
    }
    // combine the two half-wave partial sums; both halves end with identical values
    a0 += __shfl_xor(a0, 32, 64);
    a1 += __shfl_xor(a1, 32, 64);
    float si = dsin[node];
    float2 bb = *reinterpret_cast<const float2*>(&b2[c2]);
    float l0 = a0 * si + bb.x;
    float l1 = a1 * si + bb.y;
    float m = fmaxf(l0, l1);
    for (int o = 16; o > 0; o >>= 1) m = fmaxf(m, __shfl_xor(m, o, 64));
    float e0 = __expf(l0 - m), e1 = __expf(l1 - m);
    float s = e0 + e1;
    for (int o = 16; o > 0; o >>= 1) s += __shfl_xor(s, o, 64);
    float inv = 1.0f / s;
    if (half == 0) {
        *reinterpret_cast<float2*>(&out[(size_t)node * OUT_DIM + c2]) =
            make_float2(e0 * inv, e1 * inv);
        *reinterpret_cast<float2*>(&out[(size_t)NN * OUT_DIM + (size_t)node * OUT_DIM + c2]) =
            make_float2(l0, l1);
    }
}

static inline size_t align_up(size_t x, size_t a) { return (x + a - 1) & ~(a - 1); }

extern "C" void kernel_launch(void* const* d_in, const int* in_sizes, int n_in,
                              void* d_out, int out_size, void* d_ws, size_t ws_size,
                              hipStream_t stream) {
    (void)in_sizes; (void)n_in; (void)out_size;
    const float* h = (const float*)d_in[0];
    const float* W1 = (const float*)d_in[1];
    const float* b1 = (const float*)d_in[2];
    const float* W2 = (const float*)d_in[3];
    const float* b2 = (const float*)d_in[4];
    const int* src = (const int*)d_in[5];
    const int* dst = (const int*)d_in[6];
    float* out = (float*)d_out;

    char* ws = (char*)d_ws;
    size_t off = 0;
    auto alloc = [&](size_t bytes) {
        void* p = (void*)(ws + off);
        off = align_up(off + bytes, 512);
        return p;
    };
    unsigned* cnt_out = (unsigned*)alloc(NN * 4);
    unsigned* bcursor = (unsigned*)alloc(NB * 4);
    unsigned* rsinfo = (unsigned*)alloc(NN * 4);
    float* dsin = (float*)alloc(NN * 4);
    unsigned* ebuf = (unsigned*)alloc((size_t)NB * CAP * 4);
    int* csr = (int*)alloc((size_t)NB * CAP * 4);
    unsigned short* W1t = (unsigned short*)alloc((size_t)HID_DIM * IN_DIM * 2);
    unsigned short* W2t = (unsigned short*)alloc((size_t)OUT_DIM * HID_DIM * 2);
    unsigned short* feat1 = (unsigned short*)alloc((size_t)NN * HID_DIM * 2);
    unsigned short* xs = (unsigned short*)alloc((size_t)NN * HID_DIM * 2);
    unsigned short* feat2 = feat1;  // alias: feat1 dead after spmm1

    if (off > ws_size) {
        fprintf(stderr, "kernel_launch: ws too small: need %zu, have %zu\n", off, ws_size);
        return;
    }

    init_kernel<<<(NN + 255) / 256, 256, 0, stream>>>(cnt_out, bcursor);
    prep_w_kernel<<<(HID_DIM * IN_DIM + OUT_DIM * HID_DIM + 255) / 256, 256, 0, stream>>>(
        W1, W2, W1t, W2t);

    scat_kernel<<<(NE + EPB - 1) / EPB, 256, 0, stream>>>(src, dst, cnt_out, bcursor, ebuf);
    bsort_kernel<<<NB, 256, 0, stream>>>(ebuf, bcursor, csr, rsinfo, dsin);

    gemm1_kernel<<<(NN + 127) / 128, 256, 0, stream>>>(h, W1t, cnt_out, feat1, NN);
    spmm1_kernel<<<(NN + 3) / 4, 256, 0, stream>>>(feat1, csr, rsinfo, dsin, cnt_out, b1, xs);
    gemm2_kernel<<<(NN + 127) / 128, 256, 0, stream>>>(xs, W2t, feat2, NN);
    spmm2_kernel<<<(NN + 3) / 4, 256, 0, stream>>>(feat2, csr, rsinfo, dsin, b2, out);
}